// Round 8
// baseline (614.954 us; speedup 1.0000x reference)
//
#include <hip/hip_runtime.h>
#include <math.h>

// SpectralAttention gfx950 — round 8: R7 plan with the __exp2f -> exp2f fix
// (glibc math.h macro collision; exp2f lowers to v_exp_f32 on gfx950 anyway).
// Real-pair FFT (Hermitian unpack), prep folded into GEMM staging, exp2
// softmax, balanced K/V staging. Flash structure = R6 (2-barrier, s-step 64).
// B=2, T=2048, C=1024, H=16, HD=64.
//
// Packed split (u32): lo16 = fp16(v), hi16 = fp16((v-hi)*2048). 3-term MFMA:
// D = Ah*Bh + (Ah*Bl + Al*Bh)/2048.
//
// ws layout (floats):
//   [0,  4M)  qT fp32 -> qpk      [4M, 8M)  kT -> kpk    [8M, 12M) vT -> vpk
//   [12M,16M) qipk (fft)          [16M,20M) kipk
//   [20M,24M) attpk (flash)       24M: tables
// total 96 MB + 16 KB

typedef _Float16 half8 __attribute__((ext_vector_type(8)));
typedef float f32x4 __attribute__((ext_vector_type(4)));
#define MFMA16 __builtin_amdgcn_mfma_f32_16x16x32_f16

__device__ inline unsigned pack_split(float v) {
    _Float16 h = (_Float16)v;
    float r = (v - (float)h) * 2048.0f;
    _Float16 l = (_Float16)r;
    union { _Float16 f; unsigned short u; } a, b;
    a.f = h; b.f = l;
    return (unsigned)a.u | ((unsigned)b.u << 16);
}
__device__ inline _Float16 lo16(unsigned u) {
    union { unsigned short s; _Float16 f; } x; x.s = (unsigned short)(u & 0xffffu); return x.f;
}
__device__ inline _Float16 hi16(unsigned u) {
    union { unsigned short s; _Float16 f; } x; x.s = (unsigned short)(u >> 16); return x.f;
}

// split 8 packed u32 into hi/lo half8 via byte-perms, store as 2 b128
__device__ inline void write_split(_Float16* dh, _Float16* dl, uint4 u0, uint4 u1) {
    uint4 lo, hi;
    lo.x = __builtin_amdgcn_perm(u0.y, u0.x, 0x05040100u);
    lo.y = __builtin_amdgcn_perm(u0.w, u0.z, 0x05040100u);
    lo.z = __builtin_amdgcn_perm(u1.y, u1.x, 0x05040100u);
    lo.w = __builtin_amdgcn_perm(u1.w, u1.z, 0x05040100u);
    hi.x = __builtin_amdgcn_perm(u0.y, u0.x, 0x07060302u);
    hi.y = __builtin_amdgcn_perm(u0.w, u0.z, 0x07060302u);
    hi.z = __builtin_amdgcn_perm(u1.y, u1.x, 0x07060302u);
    hi.w = __builtin_amdgcn_perm(u1.w, u1.z, 0x07060302u);
    *(uint4*)dh = lo;
    *(uint4*)dl = hi;
}

// split 8 fp32 into hi/lo half8 (lo pre-scaled x2048), store as 2 b128
__device__ inline void split_store(_Float16* dh, _Float16* dl, const float* v) {
    half8 h, l;
#pragma unroll
    for (int j = 0; j < 8; ++j) {
        _Float16 hj = (_Float16)v[j];
        h[j] = hj;
        l[j] = (_Float16)((v[j] - (float)hj) * 2048.0f);
    }
    *(half8*)dh = h;
    *(half8*)dl = l;
}

// ---------------------------------------------------------------- init tables
__global__ __launch_bounds__(256) void k_init_tables(
    float2* __restrict__ tw, float2* __restrict__ filt,
    const float* __restrict__ fd, const float* __restrict__ alpha,
    const float* __restrict__ fas)
{
    int i = blockIdx.x * 256 + threadIdx.x;
    double aa = (double)alpha[0] + (double)fas[0] * ((double)fd[0] - 1.5);
    if (i < 1024) {
        double ang = -2.0 * 3.14159265358979323846 * (double)i / 2048.0;
        double s, c;
        sincos(ang, &s, &c);
        tw[i] = make_float2((float)c, (float)s);
    }
    if (i < 2048) {
        double fr = (i < 1024) ? (double)i / 2048.0 : ((double)i - 2048.0) / 2048.0;
        double ph = aa * atan(log(fabs(fr) + 1e-10));
        double s, c;
        sincos(ph, &s, &c);
        filt[i] = make_float2((float)c, (float)s);
    }
}

// --------------------------------------------------- QKV GEMM (MFMA f16-split)
// out^T[c][t] = W^T X^T, reading fp32 W (transposed on the fly) and fp32 x,
// splitting to f16 hi/lo during LDS staging. 128x128 tile, 2 barriers/K-step.
__global__ __launch_bounds__(256) void k_gemm_qkv(
    const float* __restrict__ x,
    const float* __restrict__ wq, const float* __restrict__ wk,
    const float* __restrict__ wv,
    const float* __restrict__ bq, const float* __restrict__ bk,
    const float* __restrict__ bv,
    float* __restrict__ qT, float* __restrict__ kT, float* __restrict__ vT)
{
    __shared__ __align__(16) _Float16 Ab[8][2][64][8];   // 16 KB
    __shared__ __align__(16) _Float16 Bb[8][2][64][8];   // 16 KB
    const int tid = threadIdx.x;
    const int mat = blockIdx.z;
    const float* W    = (mat == 0) ? wq : (mat == 1) ? wk : wv;
    const float* bias = (mat == 0) ? bq : (mat == 1) ? bk : bv;
    float* outp       = (mat == 0) ? qT : (mat == 1) ? kT : vT;
    const int m0 = blockIdx.x * 128, n0 = blockIdx.y * 128;
    const int w = tid >> 6, lane = tid & 63, quad = lane >> 4, l15 = lane & 15;
    const int wm = (w & 1) * 4, wn = (w >> 1) * 4;

    const int chA = tid & 3, rA = tid >> 2;
    const int flA = (rA & 15) + 16 * chA, mtA = rA >> 4;
    const float* gA  = W + (size_t)(chA * 8) * 1024 + m0 + rA;   // W[k][c]
    const float* gB0 = x + (size_t)(n0 + rA) * 1024 + chA * 8;
    const float* gB1 = gB0 + (size_t)64 * 1024;

    float a0[8], a1[8], b0[8], b1[8];
#pragma unroll
    for (int j = 0; j < 8; ++j) {
        a0[j] = gA[(size_t)j * 1024];
        a1[j] = gA[(size_t)j * 1024 + 64];
    }
    *(float4*)&b0[0] = *(const float4*)gB0;
    *(float4*)&b0[4] = *(const float4*)(gB0 + 4);
    *(float4*)&b1[0] = *(const float4*)gB1;
    *(float4*)&b1[4] = *(const float4*)(gB1 + 4);

    f32x4 acc1[4][4], acc2[4][4];
    const f32x4 z4 = {0.f, 0.f, 0.f, 0.f};
#pragma unroll
    for (int i = 0; i < 4; ++i)
#pragma unroll
        for (int j = 0; j < 4; ++j) { acc1[i][j] = z4; acc2[i][j] = z4; }

    for (int k0 = 0; k0 < 1024; k0 += 32) {
        __syncthreads();
        split_store(&Ab[mtA][0][flA][0],     &Ab[mtA][1][flA][0],     a0);
        split_store(&Ab[mtA + 4][0][flA][0], &Ab[mtA + 4][1][flA][0], a1);
        split_store(&Bb[mtA][0][flA][0],     &Bb[mtA][1][flA][0],     b0);
        split_store(&Bb[mtA + 4][0][flA][0], &Bb[mtA + 4][1][flA][0], b1);
        __syncthreads();
        if (k0 < 992) {
            const int kn = k0 + 32;
#pragma unroll
            for (int j = 0; j < 8; ++j) {
                a0[j] = gA[(size_t)(kn + j) * 1024];
                a1[j] = gA[(size_t)(kn + j) * 1024 + 64];
            }
            *(float4*)&b0[0] = *(const float4*)(gB0 + kn);
            *(float4*)&b0[4] = *(const float4*)(gB0 + kn + 4);
            *(float4*)&b1[0] = *(const float4*)(gB1 + kn);
            *(float4*)&b1[4] = *(const float4*)(gB1 + kn + 4);
        }
        half8 ah[4], al[4];
#pragma unroll
        for (int mt = 0; mt < 4; ++mt) {
            ah[mt] = *(half8*)&Ab[wm + mt][0][lane][0];
            al[mt] = *(half8*)&Ab[wm + mt][1][lane][0];
        }
#pragma unroll
        for (int nt = 0; nt < 4; ++nt) {
            half8 bh = *(half8*)&Bb[wn + nt][0][lane][0];
            half8 bl = *(half8*)&Bb[wn + nt][1][lane][0];
#pragma unroll
            for (int mt = 0; mt < 4; ++mt) {
                acc1[mt][nt] = MFMA16(ah[mt], bh, acc1[mt][nt], 0, 0, 0);
                acc2[mt][nt] = MFMA16(ah[mt], bl, acc2[mt][nt], 0, 0, 0);
                acc2[mt][nt] = MFMA16(al[mt], bh, acc2[mt][nt], 0, 0, 0);
            }
        }
    }
    const int b_ = n0 >> 11, t0 = n0 & 2047;
#pragma unroll
    for (int mt = 0; mt < 4; ++mt) {
#pragma unroll
        for (int r_ = 0; r_ < 4; ++r_) {
            int m = m0 + (wm + mt) * 16 + quad * 4 + r_;
            float bs = bias[m];
            float* orow = &outp[(size_t)(b_ * 1024 + m) * 2048 + t0];
#pragma unroll
            for (int nt = 0; nt < 4; ++nt) {
                float val = acc1[mt][nt][r_] + acc2[mt][nt][r_] * (1.f / 2048.f) + bs;
                orow[(wn + nt) * 16 + l15] = val;
            }
        }
    }
}

// ------------------------------------------------- FFT + filter (real pairs)
// One block per (mat, b, channel-pair). z = x_c + i*x_{c+1}; one complex FFT;
// Hermitian unpack (filt[N-k] == filt[k] exactly) produces freq i and 2048-i
// for both channels. Writes packed-split u32 in place.
__global__ __launch_bounds__(256) void k_fft_filter(
    float* __restrict__ qT, float* __restrict__ kT, float* __restrict__ vT,
    float* __restrict__ qiT, float* __restrict__ kiT,
    const float2* __restrict__ tw, const float2* __restrict__ filt)
{
    __shared__ float2 sf[2048];
    const int bid = blockIdx.x;          // 0..3071
    const int mat = bid >> 10;
    const int pr  = bid & 1023;
    const int b   = pr >> 9;
    const int cc  = (pr & 511) * 2;
    float* base = (mat == 0) ? qT : (mat == 1) ? kT : vT;
    const size_t row0 = (size_t)(b * 1024 + cc) * 2048;
    const float* s0p = base + row0;
    const float* s1p = s0p + 2048;
    const int tid = threadIdx.x;

    for (int i = tid; i < 2048; i += 256) {
        int j = (int)(__brev((unsigned)i) >> 21);
        sf[j] = make_float2(s0p[i], s1p[i]);
    }
    __syncthreads();
    for (int st = 1; st <= 11; ++st) {
        const int half = 1 << (st - 1);
        const int shift = 11 - st;
        for (int u = tid; u < 1024; u += 256) {
            int pos = u & (half - 1);
            int bi = 2 * u - pos;
            float2 w = tw[pos << shift];
            float2 a = sf[bi], bb = sf[bi + half];
            float tr = w.x * bb.x - w.y * bb.y;
            float ti = w.x * bb.y + w.y * bb.x;
            sf[bi]        = make_float2(a.x + tr, a.y + ti);
            sf[bi + half] = make_float2(a.x - tr, a.y - ti);
        }
        __syncthreads();
    }
    unsigned* re0 = (unsigned*)base + row0;
    unsigned* re1 = re0 + 2048;
    unsigned* im0 = (mat == 0) ? (unsigned*)qiT + row0
                               : (unsigned*)kiT + row0;   // unused for mat 2
    unsigned* im1 = im0 + 2048;
    const float SC = 0.18033688f;   // 0.125 * log2(e): exp2 softmax units

    for (int i = tid; i <= 1024; i += 256) {
        int j = (2048 - i) & 2047;
        float2 Zi = sf[i], Zj = sf[j];
        float F0r = 0.5f * (Zi.x + Zj.x), F0i = 0.5f * (Zi.y - Zj.y);
        float F1r = 0.5f * (Zi.y + Zj.y), F1i = 0.5f * (Zj.x - Zi.x);
        float2 f = filt[i];
        float a0r = F0r * f.x - F0i * f.y, a0i = F0r * f.y + F0i * f.x;
        float b0r = F0r * f.x + F0i * f.y, b0i = F0r * f.y - F0i * f.x;
        float a1r = F1r * f.x - F1i * f.y, a1i = F1r * f.y + F1i * f.x;
        float b1r = F1r * f.x + F1i * f.y, b1i = F1r * f.y - F1i * f.x;
        if (mat == 0) {
            re0[i] = pack_split(SC * a0r); im0[i] = pack_split(SC * a0i);
            re1[i] = pack_split(SC * a1r); im1[i] = pack_split(SC * a1i);
            if (j != i) {
                re0[j] = pack_split(SC * b0r); im0[j] = pack_split(SC * b0i);
                re1[j] = pack_split(SC * b1r); im1[j] = pack_split(SC * b1i);
            }
        } else if (mat == 1) {
            re0[i] = pack_split(a0r); im0[i] = pack_split(-a0i);
            re1[i] = pack_split(a1r); im1[i] = pack_split(-a1i);
            if (j != i) {
                re0[j] = pack_split(b0r); im0[j] = pack_split(-b0i);
                re1[j] = pack_split(b1r); im1[j] = pack_split(-b1i);
            }
        } else {
            re0[i] = pack_split(a0r); re1[i] = pack_split(a1r);
            if (j != i) { re0[j] = pack_split(b0r); re1[j] = pack_split(b1r); }
        }
    }
}

// ------------------------------------------------------------- flash (MFMA f16)
// 512 thr = 8 waves; block = (bh, t-tile 128); s-step 64; 2 barriers/iter.
// exp2 softmax (log2e folded into q scale); balanced K+V staging (all 512 thr).
__global__ __launch_bounds__(512) void k_flash(
    const unsigned* __restrict__ qpk, const unsigned* __restrict__ qipk,
    const unsigned* __restrict__ kpk, const unsigned* __restrict__ kipk,
    const unsigned* __restrict__ vpk, unsigned* __restrict__ attpk)
{
    __shared__ __align__(16) _Float16 Kbuf[4][4][2][64][8];  // 32KB
    __shared__ __align__(16) _Float16 Vbuf[2][4][2][64][8];  // 16KB
    __shared__ __align__(16) _Float16 Pbuf[8][16][64];       // 16KB

    const int tid = threadIdx.x;
    const int w = tid >> 6, lane = tid & 63;
    const int quad = lane >> 4, l15 = lane & 15;
    const int bh = blockIdx.x >> 4, tb = blockIdx.x & 15;
    const size_t bc = (size_t)bh * 64;
    const int tw0 = tb * 128 + w * 16;

    half8 aqh[4], aql[4];
#pragma unroll
    for (int kc = 0; kc < 4; ++kc) {
#pragma unroll
        for (int j = 0; j < 8; ++j) {
            int d = kc * 32 + quad * 8 + j;
            int t = tw0 + l15;
            unsigned u = (d < 64) ? qpk[(bc + d) * 2048 + t]
                                  : qipk[(bc + d - 64) * 2048 + t];
            aqh[kc][j] = lo16(u);
            aql[kc][j] = hi16(u);
        }
    }

    f32x4 O1[4], O2[4];
    const f32x4 zero4 = {0.f, 0.f, 0.f, 0.f};
#pragma unroll
    for (int nt = 0; nt < 4; ++nt) { O1[nt] = zero4; O2[nt] = zero4; }
    float m_[4] = {-3e38f, -3e38f, -3e38f, -3e38f};
    float l_[4] = {0.f, 0.f, 0.f, 0.f};

    // K staging: task0 -> real plane, task1 -> imag plane, coalesced over s
    const int sK = tid & 63;
    const int dc0 = tid >> 6;          // 0..7
    const int stK = sK >> 4;
    const int kcK0 = dc0 >> 2;         // 0..1; imag task kc = kcK0+2
    const int laneK = (sK & 15) + ((dc0 & 3) << 4);
    const unsigned* kre = &kpk[(bc + dc0 * 8) * 2048 + sK];
    const unsigned* kim = &kipk[(bc + dc0 * 8) * 2048 + sK];
    // V staging: all 512 threads, one (d, 8s) chunk each
    const int dV = tid & 63, mV = tid >> 6;          // mV 0..7
    const int sc2V = mV >> 2, gV = mV & 3;
    const int ntV = dV >> 4;
    const int laneV = (dV & 15) + (gV << 4);
    const unsigned* vbase = &vpk[(bc + dV) * 2048 + mV * 8];

    for (int it = 0; it < 32; ++it) {
        const int s0 = it * 64;
        __syncthreads();                     // prior compute reads done
        unsigned ka[8], kb2[8];
#pragma unroll
        for (int j = 0; j < 8; ++j) ka[j]  = kre[(size_t)j * 2048 + s0];
#pragma unroll
        for (int j = 0; j < 8; ++j) kb2[j] = kim[(size_t)j * 2048 + s0];
        uint4 va0 = *(const uint4*)(vbase + s0);
        uint4 va1 = *(const uint4*)(vbase + s0 + 4);
        write_split(&Kbuf[stK][kcK0][0][laneK][0], &Kbuf[stK][kcK0][1][laneK][0],
                    *(uint4*)&ka[0], *(uint4*)&ka[4]);
        write_split(&Kbuf[stK][kcK0 + 2][0][laneK][0], &Kbuf[stK][kcK0 + 2][1][laneK][0],
                    *(uint4*)&kb2[0], *(uint4*)&kb2[4]);
        write_split(&Vbuf[sc2V][ntV][0][laneV][0], &Vbuf[sc2V][ntV][1][laneV][0],
                    va0, va1);
        __syncthreads();

        // --- S = Q.K^T (3-term split): 48 MFMA
        f32x4 S1[4], S2[4];
#pragma unroll
        for (int st = 0; st < 4; ++st) { S1[st] = zero4; S2[st] = zero4; }
#pragma unroll
        for (int st = 0; st < 4; ++st) {
#pragma unroll
            for (int kc = 0; kc < 4; ++kc) {
                half8 bhf = *(half8*)&Kbuf[st][kc][0][lane][0];
                half8 blf = *(half8*)&Kbuf[st][kc][1][lane][0];
                S1[st] = MFMA16(aqh[kc], bhf, S1[st], 0, 0, 0);
                S2[st] = MFMA16(aqh[kc], blf, S2[st], 0, 0, 0);
                S2[st] = MFMA16(aql[kc], bhf, S2[st], 0, 0, 0);
            }
        }

        // --- online softmax in log2 units
#pragma unroll
        for (int r = 0; r < 4; ++r) {
            float v0 = S1[0][r] + S2[0][r] * (1.f / 2048.f);
            float v1 = S1[1][r] + S2[1][r] * (1.f / 2048.f);
            float v2 = S1[2][r] + S2[2][r] * (1.f / 2048.f);
            float v3 = S1[3][r] + S2[3][r] * (1.f / 2048.f);
            float mt = fmaxf(fmaxf(v0, v1), fmaxf(v2, v3));
#pragma unroll
            for (int msk = 1; msk < 16; msk <<= 1)
                mt = fmaxf(mt, __shfl_xor(mt, msk, 16));
            float mn = fmaxf(m_[r], mt);
            float al = exp2f(m_[r] - mn);
            m_[r] = mn;
            float p0 = exp2f(v0 - mn);
            float p1 = exp2f(v1 - mn);
            float p2 = exp2f(v2 - mn);
            float p3 = exp2f(v3 - mn);
            float rs = (p0 + p1) + (p2 + p3);
#pragma unroll
            for (int msk = 1; msk < 16; msk <<= 1)
                rs += __shfl_xor(rs, msk, 16);
            l_[r] = l_[r] * al + rs;
#pragma unroll
            for (int nt = 0; nt < 4; ++nt) { O1[nt][r] *= al; O2[nt][r] *= al; }
            int t = quad * 4 + r;
            Pbuf[w][t][l15]      = (_Float16)p0;
            Pbuf[w][t][l15 + 16] = (_Float16)p1;
            Pbuf[w][t][l15 + 32] = (_Float16)p2;
            Pbuf[w][t][l15 + 48] = (_Float16)p3;
        }
        // Pbuf is wave-private: no barrier needed

        // --- PV accumulate: 16 MFMA
#pragma unroll
        for (int sc2 = 0; sc2 < 2; ++sc2) {
            half8 ap = *(half8*)&Pbuf[w][l15][sc2 * 32 + quad * 8];
#pragma unroll
            for (int nt = 0; nt < 4; ++nt) {
                half8 vh = *(half8*)&Vbuf[sc2][nt][0][lane][0];
                half8 vl = *(half8*)&Vbuf[sc2][nt][1][lane][0];
                O1[nt] = MFMA16(ap, vh, O1[nt], 0, 0, 0);
                O2[nt] = MFMA16(ap, vl, O2[nt], 0, 0, 0);
            }
        }
    }

    const int b = bh >> 4, h = bh & 15;
#pragma unroll
    for (int r = 0; r < 4; ++r) {
        float inv = 1.0f / l_[r];
        int t = tw0 + quad * 4 + r;
        size_t row = (size_t)b * 2048 + t;
#pragma unroll
        for (int nt = 0; nt < 4; ++nt) {
            float val = (O1[nt][r] + O2[nt][r] * (1.f / 2048.f)) * inv;
            attpk[row * 1024 + h * 64 + nt * 16 + l15] = pack_split(val);
        }
    }
}

// --------------------------------------------------- out GEMM (MFMA f16-split)
// out[t][c] = att @ wo + bo. A = attpk (packed), B = wo fp32 transposed-on-stage.
__global__ __launch_bounds__(256) void k_gemm_out(
    const unsigned* __restrict__ attpk, const float* __restrict__ wo,
    const float* __restrict__ bo, float* __restrict__ out)
{
    __shared__ __align__(16) _Float16 Ab[8][2][64][8];
    __shared__ __align__(16) _Float16 Bb[8][2][64][8];
    const int tid = threadIdx.x;
    const int m0 = blockIdx.x * 128, n0 = blockIdx.y * 128;
    const int w = tid >> 6, lane = tid & 63, quad = lane >> 4, l15 = lane & 15;
    const int wm = (w & 1) * 4, wn = (w >> 1) * 4;

    const int chA = tid & 3, rA = tid >> 2;
    const int flA = (rA & 15) + 16 * chA, mtA = rA >> 4;
    const unsigned* gA0 = &attpk[(size_t)(m0 + rA) * 1024 + chA * 8];
    const unsigned* gA1 = gA0 + (size_t)64 * 1024;
    const float* gB = wo + (size_t)(chA * 8) * 1024 + n0 + rA;   // wo[k][c]

    uint4 pa0 = *(const uint4*)gA0, pa1 = *(const uint4*)(gA0 + 4);
    uint4 pa2 = *(const uint4*)gA1, pa3 = *(const uint4*)(gA1 + 4);
    float b0[8], b1[8];
#pragma unroll
    for (int j = 0; j < 8; ++j) {
        b0[j] = gB[(size_t)j * 1024];
        b1[j] = gB[(size_t)j * 1024 + 64];
    }

    f32x4 acc1[4][4], acc2[4][4];
    const f32x4 z4 = {0.f, 0.f, 0.f, 0.f};
#pragma unroll
    for (int i = 0; i < 4; ++i)
#pragma unroll
        for (int j = 0; j < 4; ++j) { acc1[i][j] = z4; acc2[i][j] = z4; }

    for (int k0 = 0; k0 < 1024; k0 += 32) {
        __syncthreads();
        write_split(&Ab[mtA][0][flA][0],     &Ab[mtA][1][flA][0],     pa0, pa1);
        write_split(&Ab[mtA + 4][0][flA][0], &Ab[mtA + 4][1][flA][0], pa2, pa3);
        split_store(&Bb[mtA][0][flA][0],     &Bb[mtA][1][flA][0],     b0);
        split_store(&Bb[mtA + 4][0][flA][0], &Bb[mtA + 4][1][flA][0], b1);
        __syncthreads();
        if (k0 < 992) {
            const int kn = k0 + 32;
            pa0 = *(const uint4*)(gA0 + kn); pa1 = *(const uint4*)(gA0 + kn + 4);
            pa2 = *(const uint4*)(gA1 + kn); pa3 = *(const uint4*)(gA1 + kn + 4);
#pragma unroll
            for (int j = 0; j < 8; ++j) {
                b0[j] = gB[(size_t)(kn + j) * 1024];
                b1[j] = gB[(size_t)(kn + j) * 1024 + 64];
            }
        }
        half8 ah[4], al[4];
#pragma unroll
        for (int mt = 0; mt < 4; ++mt) {
            ah[mt] = *(half8*)&Ab[wm + mt][0][lane][0];
            al[mt] = *(half8*)&Ab[wm + mt][1][lane][0];
        }
#pragma unroll
        for (int nt = 0; nt < 4; ++nt) {
            half8 bh = *(half8*)&Bb[wn + nt][0][lane][0];
            half8 bl = *(half8*)&Bb[wn + nt][1][lane][0];
#pragma unroll
            for (int mt = 0; mt < 4; ++mt) {
                acc1[mt][nt] = MFMA16(ah[mt], bh, acc1[mt][nt], 0, 0, 0);
                acc2[mt][nt] = MFMA16(ah[mt], bl, acc2[mt][nt], 0, 0, 0);
                acc2[mt][nt] = MFMA16(al[mt], bh, acc2[mt][nt], 0, 0, 0);
            }
        }
    }
#pragma unroll
    for (int mt = 0; mt < 4; ++mt) {
#pragma unroll
        for (int r_ = 0; r_ < 4; ++r_) {
            int m = m0 + (wm + mt) * 16 + quad * 4 + r_;
            float* orow = &out[(size_t)m * 1024 + n0];
#pragma unroll
            for (int nt = 0; nt < 4; ++nt) {
                int n = (wn + nt) * 16 + l15;
                float val = acc1[mt][nt][r_] + acc2[mt][nt][r_] * (1.f / 2048.f)
                          + bo[n0 + n];
                orow[n] = val;
            }
        }
    }
}

// ------------------------------------------------------------- energy renorm
__global__ __launch_bounds__(256) void k_norm(
    const float* __restrict__ x, float* __restrict__ out,
    const float* __restrict__ en)
{
    const int row = blockIdx.x;
    const int tid = threadIdx.x;
    const float* xr = x + (size_t)row * 1024;
    float* orow = out + (size_t)row * 1024;
    float4 xv = *(const float4*)&xr[tid * 4];
    float4 ov = *(const float4*)&orow[tid * 4];
    float ssx = xv.x * xv.x + xv.y * xv.y + xv.z * xv.z + xv.w * xv.w;
    float sso = ov.x * ov.x + ov.y * ov.y + ov.z * ov.z + ov.w * ov.w;
#pragma unroll
    for (int m = 1; m <= 32; m <<= 1) {
        ssx += __shfl_xor(ssx, m, 64);
        sso += __shfl_xor(sso, m, 64);
    }
    __shared__ float rx[4], ro[4];
    const int wid = tid >> 6;
    if ((tid & 63) == 0) { rx[wid] = ssx; ro[wid] = sso; }
    __syncthreads();
    float tsx = rx[0] + rx[1] + rx[2] + rx[3];
    float tso = ro[0] + ro[1] + ro[2] + ro[3];
    float scale = sqrtf(tsx) / (sqrtf(tso) + 1e-8f) * en[0];
    ov.x *= scale; ov.y *= scale; ov.z *= scale; ov.w *= scale;
    *(float4*)&orow[tid * 4] = ov;
}

// ------------------------------------------------------------- launch
extern "C" void kernel_launch(void* const* d_in, const int* in_sizes, int n_in,
                              void* d_out, int out_size, void* d_ws, size_t ws_size,
                              hipStream_t stream)
{
    const float* x     = (const float*)d_in[0];
    const float* fd    = (const float*)d_in[1];
    const float* wq    = (const float*)d_in[2];
    const float* bq    = (const float*)d_in[3];
    const float* wk    = (const float*)d_in[4];
    const float* bk    = (const float*)d_in[5];
    const float* wv    = (const float*)d_in[6];
    const float* bv    = (const float*)d_in[7];
    const float* wo    = (const float*)d_in[8];
    const float* bo    = (const float*)d_in[9];
    const float* alpha = (const float*)d_in[10];
    const float* fas   = (const float*)d_in[11];
    const float* en    = (const float*)d_in[12];
    float* out = (float*)d_out;
    float* ws  = (float*)d_ws;

    float* qT  = ws;                               // -> qpk
    float* kT  = ws + (size_t)1 * 4194304;         // -> kpk
    float* vT  = ws + (size_t)2 * 4194304;         // -> vpk
    float* qiT = ws + (size_t)3 * 4194304;         // qipk
    float* kiT = ws + (size_t)4 * 4194304;         // kipk
    float* att = ws + (size_t)5 * 4194304;         // attpk
    float2* tw   = (float2*)(ws + (size_t)6 * 4194304);
    float2* filt = (float2*)(ws + (size_t)6 * 4194304 + 2048);

    unsigned* attpk = (unsigned*)att;

    k_init_tables<<<8, 256, 0, stream>>>(tw, filt, fd, alpha, fas);
    k_gemm_qkv<<<dim3(8, 32, 3), 256, 0, stream>>>(x, wq, wk, wv, bq, bk, bv,
                                                   qT, kT, vT);
    k_fft_filter<<<3072, 256, 0, stream>>>(qT, kT, vT, qiT, kiT, tw, filt);
    k_flash<<<512, 512, 0, stream>>>((const unsigned*)qT, (const unsigned*)qiT,
                                     (const unsigned*)kT, (const unsigned*)kiT,
                                     (const unsigned*)vT, attpk);
    k_gemm_out<<<dim3(32, 8), 256, 0, stream>>>(attpk, wo, bo, out);
    k_norm<<<4096, 256, 0, stream>>>(x, out, en);
}